// Round 13
// baseline (53381.348 us; speedup 1.0000x reference)
//
#include <hip/hip_runtime.h>
#include <cstdint>
#include <cstddef>

// GRU decoder w/ Bahdanau attention, B=64 L=512 E=128 H=512 ENC=256 V=4 NL=2.
// R13: SEQUENTIAL MULTI-KERNEL — 4 small kernels per step (2048 launches,
// graph-captured). Kernel boundaries provide device-wide sync + coherence
// (~2-4us each) instead of the ~30us in-kernel cross-block crossings measured
// in R3-R12. Normal cached loads only; weights/keys/encT L3-resident.
// Numerics: f16 weights + v_dot2_f32_f16 (R10/R12-proven), f16 keys (R10),
// no-max softmax (R7-12), f32 state/q.

#define BB   64
#define LL   512
#define EE   128
#define HH   512
#define ED   256
#define VV   4
#define SOS  4

typedef unsigned short ushort8 __attribute__((ext_vector_type(8)));
typedef unsigned int uint;
typedef _Float16 h2v __attribute__((ext_vector_type(2)));

// ---------------- ws layout (bytes) ----------------
static const size_t OFF_KEYS = 0;          // f16 [64][512][512]  33,554,432
static const size_t OFF_ENCT = 33554432;   // f16 [64][256][512]  16,777,216
static const size_t OFF_WHF  = 50331648;   // f16 [512][512]         524,288
static const size_t OFF_W0F  = 50855936;   // f16 [1536][512]      1,572,864
static const size_t OFF_W1F  = 52428800;   // f16 [1536][512]      1,572,864
static const size_t OFF_WI1F = 54001664;   // f16 [1536][512]      1,572,864
static const size_t OFF_WICF = 55574528;   // f16 [1536][256]        786,432
static const size_t OFF_GTOK = 56360960;   // f32 [6][1536]           36,864
static const size_t OFF_H0   = 56397824;   // f32 [64][512]          131,072
static const size_t OFF_H1   = 56528896;   // f32 [64][512]          131,072
static const size_t OFF_Q    = 56659968;   // f32 [64][512]          131,072
static const size_t OFF_GH0  = 56791040;   // f32 [64][1536]         393,216
static const size_t OFF_GH1  = 57184256;   // f32 [64][1536]         393,216
static const size_t OFF_CTXP = 57577472;   // f32 [64][8][256]       524,288
static const size_t OFF_SSP  = 58101760;   // f32 [64][8]              2,048
// end ~58.1 MB

// padded q index: quarter p starts at p*136 floats
__device__ __forceinline__ int qidx(int h) { return h + ((h >> 7) << 3); }

// ---------------- helpers ----------------
__device__ __forceinline__ float h2f(unsigned short u) {
  return (float)__builtin_bit_cast(_Float16, u);
}
__device__ __forceinline__ unsigned short f2h(float f) {
  return __builtin_bit_cast(unsigned short, (_Float16)f);
}
__device__ __forceinline__ uint packh(float a, float b) {
  return (uint)f2h(a) | ((uint)f2h(b) << 16);
}
__device__ __forceinline__ float fd2(uint w, uint h, float acc) {
#if __has_builtin(__builtin_amdgcn_fdot2)
  return __builtin_amdgcn_fdot2(__builtin_bit_cast(h2v, w),
                                __builtin_bit_cast(h2v, h), acc, false);
#else
  acc += h2f((unsigned short)(w & 0xffffu)) * h2f((unsigned short)(h & 0xffffu));
  acc += h2f((unsigned short)(w >> 16)) * h2f((unsigned short)(h >> 16));
  return acc;
#endif
}
__device__ __forceinline__ float tanh_fast(float x) {
  x = __builtin_amdgcn_fmed3f(x, -10.f, 10.f);
  float t = __builtin_amdgcn_exp2f(x * 2.8853900817779268f);
  return (t - 1.f) * __builtin_amdgcn_rcpf(t + 1.f);
}
__device__ __forceinline__ float sigmoid_fast(float x) {
  x = __builtin_amdgcn_fmed3f(x, -30.f, 30.f);
  float t = __builtin_amdgcn_exp2f(x * -1.4426950408889634f);
  return __builtin_amdgcn_rcpf(1.f + t);
}
__device__ __forceinline__ float exp_fast(float x) {
  return __builtin_amdgcn_exp2f(x * 1.4426950408889634f);
}

// ---------------- precompute kernels ----------------

// weights -> f16 (WIC = Wih0[:,128:384])
__global__ void k_prep(const float* Wh, const float* Whh0, const float* Whh1,
                       const float* Wih1, const float* Wih0, char* ws) {
  unsigned short* WHF  = (unsigned short*)(ws + OFF_WHF);
  unsigned short* W0F  = (unsigned short*)(ws + OFF_W0F);
  unsigned short* W1F  = (unsigned short*)(ws + OFF_W1F);
  unsigned short* WI1F = (unsigned short*)(ws + OFF_WI1F);
  unsigned short* WICF = (unsigned short*)(ws + OFF_WICF);
  const int tot = 262144 + 786432 * 3 + 393216;
  for (int i = blockIdx.x * blockDim.x + threadIdx.x; i < tot; i += gridDim.x * blockDim.x) {
    if (i < 262144) WHF[i] = f2h(Wh[i]);
    else if (i < 262144 + 786432) { int j = i - 262144; W0F[j] = f2h(Whh0[j]); }
    else if (i < 262144 + 2 * 786432) { int j = i - 262144 - 786432; W1F[j] = f2h(Whh1[j]); }
    else if (i < 262144 + 3 * 786432) { int j = i - 262144 - 2 * 786432; WI1F[j] = f2h(Wih1[j]); }
    else {
      int j = i - 262144 - 3 * 786432;
      int r = j >> 8, e = j & 255;
      WICF[j] = f2h(Wih0[(size_t)r * 384 + 128 + e]);
    }
  }
}

// keys[b][l][h] = f16(enc[b][l][:] . Ws[h][:])
__global__ void k_keys(const float* enc, const float* Ws, char* ws) {
  unsigned short* keys = (unsigned short*)(ws + OFF_KEYS);
  __shared__ float et[32][ED];
  const int tid = threadIdx.x;
  const int row0 = blockIdx.x * 32;
  for (int r = 0; r < 32; ++r) et[r][tid] = enc[(size_t)(row0 + r) * ED + tid];
  __syncthreads();
  for (int hhh = 0; hhh < 2; ++hhh) {
    const int h = hhh * 256 + tid;
    float acc[32];
    #pragma unroll
    for (int ll = 0; ll < 32; ++ll) acc[ll] = 0.f;
    const float4* wrow = (const float4*)(Ws + (size_t)h * ED);
    for (int e4 = 0; e4 < 64; ++e4) {
      float4 w = wrow[e4];
      #pragma unroll
      for (int ll = 0; ll < 32; ++ll) {
        acc[ll] += w.x * et[ll][e4 * 4] + w.y * et[ll][e4 * 4 + 1]
                 + w.z * et[ll][e4 * 4 + 2] + w.w * et[ll][e4 * 4 + 3];
      }
    }
    for (int ll = 0; ll < 32; ++ll)
      keys[(size_t)(row0 + ll) * HH + h] = f2h(acc[ll]);
  }
}

// enct[b][e][l] = f16(enc[b][l][e])
__global__ void k_encT(const float* enc, char* ws) {
  unsigned short* enct = (unsigned short*)(ws + OFF_ENCT);
  const int tot = BB * LL * ED;
  for (int i = blockIdx.x * blockDim.x + threadIdx.x; i < tot; i += gridDim.x * blockDim.x) {
    int b = i >> 17, l = (i >> 8) & 511, e = i & 255;
    enct[((size_t)b * ED + e) * LL + l] = f2h(enc[i]);
  }
}

// gi_tok[v][r] = bih0[r] + emb[v] . Wih0[r][0:128]   (f32)
__global__ void k_gitok(const float* emb, const float* Wih0, const float* bih0, char* ws) {
  float* gt = (float*)(ws + OFF_GTOK);
  const int vt = blockIdx.x;
  const int tid = threadIdx.x;
  __shared__ float ev[EE];
  if (tid < EE) ev[tid] = emb[(size_t)vt * EE + tid];
  __syncthreads();
  for (int r = tid; r < 1536; r += 256) {
    float a = bih0[r];
    const float* wr = Wih0 + (size_t)r * 384;
    for (int e = 0; e < EE; ++e) a += wr[e] * ev[e];
    gt[(size_t)vt * 1536 + r] = a;
  }
}

// init hidden + initial q = Wh @ h1  (f32)
__global__ void k_init(const float* enc, const float* Winit, const float* binit,
                       const float* Wh, char* ws) {
  const int b = blockIdx.x;
  const int tid = threadIdx.x; // 256
  __shared__ float pooled[ED];
  __shared__ float h1loc[HH];
  float acc = 0.f;
  for (int l = 0; l < LL; ++l) acc += enc[((size_t)b * LL + l) * ED + tid];
  pooled[tid] = acc * (1.0f / 512.0f);
  __syncthreads();
  float* h0 = (float*)(ws + OFF_H0);
  float* h1 = (float*)(ws + OFF_H1);
  for (int pass = 0; pass < 4; ++pass) {
    const int jj = pass * 256 + tid;
    float a = binit[jj];
    const float* wr = Winit + (size_t)jj * ED;
    for (int e = 0; e < ED; ++e) a += wr[e] * pooled[e];
    const float val = tanh_fast(a);
    const int nl = jj >> 9, h = jj & 511;
    if (nl == 0) h0[(size_t)b * HH + h] = val;
    else { h1[(size_t)b * HH + h] = val; h1loc[h] = val; }
  }
  __syncthreads();
  float* Q = (float*)(ws + OFF_Q);
  for (int pass = 0; pass < 2; ++pass) {
    const int r = pass * 256 + tid;
    const float* wr = Wh + (size_t)r * HH;
    float a = 0.f;
    for (int k = 0; k < HH; ++k) a += wr[k] * h1loc[k];
    Q[(size_t)b * HH + r] = a;
  }
}

// ---------------- per-step kernels ----------------

// K1: bid<512 -> attention partials (b=bid>>3, lc=bid&7);
//     bid>=512 -> gh matvecs, batch-grouped (mat, slice, bgroup).
__global__ __launch_bounds__(256) void k1(char* ws, const float* vvec,
                                          const float* bhh0, const float* bhh1) {
  __shared__ union {
    struct { float qb[544]; float vv[544]; float scb[64]; float atb[64]; } att;
    struct { uint hu[8][256]; float pRed[6 * 128 * 8]; } gh;
  } sm;
  const int bid = blockIdx.x, tid = threadIdx.x;

  if (bid < 512) {
    const int b = bid >> 3, lc = bid & 7;
    const float* Q = (const float*)(ws + OFF_Q) + (size_t)b * HH;
    sm.att.qb[qidx(tid)] = Q[tid];
    sm.att.qb[qidx(256 + tid)] = Q[256 + tid];
    sm.att.vv[qidx(tid)] = vvec[tid];
    sm.att.vv[qidx(256 + tid)] = vvec[256 + tid];
    __syncthreads();
    // scores for l = lc*64 + (tid>>2)
    {
      const int lloc = tid >> 2, hq = tid & 3;
      const unsigned short* keys = (const unsigned short*)(ws + OFF_KEYS);
      const ushort8* kr = (const ushort8*)(keys + ((size_t)(b * LL + lc * 64 + lloc) * HH + hq * 128));
      const float* qh = sm.att.qb + hq * 136;
      const float* vh = sm.att.vv + hq * 136;
      float s = 0.f;
      for (int i8 = 0; i8 < 16; ++i8) {
        ushort8 kk = kr[i8];
        #pragma unroll
        for (int u = 0; u < 8; ++u)
          s += vh[i8 * 8 + u] * tanh_fast(qh[i8 * 8 + u] + h2f(kk[u]));
      }
      s += __shfl_xor(s, 1);
      s += __shfl_xor(s, 2);
      if (hq == 0) sm.att.scb[lloc] = s;
    }
    __syncthreads();
    // exp (no max pass; |s| <= sum|v| ~ 20) + partial sum
    if (tid < 64) {
      float e = exp_fast(sm.att.scb[tid]);
      sm.att.atb[tid] = e;
      float s2 = e;
      #pragma unroll
      for (int off = 32; off >= 1; off >>= 1) s2 += __shfl_xor(s2, off);
      if (tid == 0) ((float*)(ws + OFF_SSP))[(size_t)b * 8 + lc] = s2;
    }
    __syncthreads();
    // ctx partial (unnormalized): e = tid
    {
      const unsigned short* er = (const unsigned short*)(ws + OFF_ENCT)
                                 + ((size_t)(b * ED + tid) * LL + lc * 64);
      float a = 0.f;
      for (int i8 = 0; i8 < 8; ++i8) {
        ushort8 ee = ((const ushort8*)er)[i8];
        #pragma unroll
        for (int u = 0; u < 8; ++u) a += sm.att.atb[i8 * 8 + u] * h2f(ee[u]);
      }
      ((float*)(ws + OFF_CTXP))[((size_t)b * 8 + lc) * 256 + tid] = a;
    }
  } else {
    const int idx = bid - 512;
    const int mat = idx & 1, sl = (idx >> 1) & 3, bg = idx >> 3;
    const float* hsrc = (const float*)(ws + (mat ? OFF_H1 : OFF_H0));
    const unsigned short* WF = (const unsigned short*)(ws + (mat ? OFF_W1F : OFF_W0F));
    const float* bias = mat ? bhh1 : bhh0;
    float* GHd = (float*)(ws + (mat ? OFF_GH1 : OFF_GH0));
    // pack 8 batches' h -> f16 pairs
    for (int p = 0; p < 8; ++p) {
      const int u = p * 256 + tid;
      const int b8 = u >> 8, i = u & 255;
      const float* hp = hsrc + (size_t)(bg * 8 + b8) * HH + 2 * i;
      sm.gh.hu[b8][i] = packh(hp[0], hp[1]);
    }
    __syncthreads();
    const int r = tid & 127, half = tid >> 7;
    for (int g = 0; g < 3; ++g) {
      const int row = g * 512 + sl * 128 + r;
      const uint* w = (const uint*)WF + (size_t)row * 256 + half * 128;
      float acc[8] = {0.f, 0.f, 0.f, 0.f, 0.f, 0.f, 0.f, 0.f};
      for (int c8 = 0; c8 < 32; ++c8) {
        const uint4 w4 = *(const uint4*)(w + c8 * 4);
        #pragma unroll
        for (int b8 = 0; b8 < 8; ++b8) {
          const uint4 h4 = *(const uint4*)(&sm.gh.hu[b8][half * 128 + c8 * 4]);
          acc[b8] = fd2(w4.x, h4.x, acc[b8]);
          acc[b8] = fd2(w4.y, h4.y, acc[b8]);
          acc[b8] = fd2(w4.z, h4.z, acc[b8]);
          acc[b8] = fd2(w4.w, h4.w, acc[b8]);
        }
      }
      #pragma unroll
      for (int b8 = 0; b8 < 8; ++b8)
        sm.gh.pRed[((g * 2 + half) * 128 + r) * 8 + b8] = acc[b8];
    }
    __syncthreads();
    if (tid < 128) {
      for (int g = 0; g < 3; ++g) {
        const float bv = bias[g * 512 + sl * 128 + tid];
        #pragma unroll
        for (int b8 = 0; b8 < 8; ++b8) {
          const float v = sm.gh.pRed[((g * 2 + 0) * 128 + tid) * 8 + b8]
                        + sm.gh.pRed[((g * 2 + 1) * 128 + tid) * 8 + b8] + bv;
          GHd[(size_t)(bg * 8 + b8) * 1536 + g * 512 + sl * 128 + tid] = v;
        }
      }
    }
  }
}

// K2a: ctx merge + gi0 + layer-0 gates -> H0. blocks (hs = bid>>3, bg = bid&7).
__global__ __launch_bounds__(256) void k2a(char* ws, const int* targets, int t) {
  __shared__ float ctxf[8][256];
  __shared__ uint ctxh[8][128];
  __shared__ float pRed[6 * 128 * 8];
  const int bid = blockIdx.x, tid = threadIdx.x;
  const int hs = bid >> 3, bg = bid & 7;
  const float* CTXP = (const float*)(ws + OFF_CTXP);
  const float* SSP = (const float*)(ws + OFF_SSP);
  for (int b8 = 0; b8 < 8; ++b8) {
    const int b = bg * 8 + b8;
    float S = 0.f;
    #pragma unroll
    for (int p = 0; p < 8; ++p) S += SSP[(size_t)b * 8 + p];
    float acc = 0.f;
    #pragma unroll
    for (int p = 0; p < 8; ++p) acc += CTXP[((size_t)b * 8 + p) * 256 + tid];
    ctxf[b8][tid] = acc * __builtin_amdgcn_rcpf(S);
  }
  __syncthreads();
  for (int p = 0; p < 4; ++p) {
    const int u = p * 256 + tid;
    const int b8 = u >> 7, i = u & 127;
    ctxh[b8][i] = packh(ctxf[b8][2 * i], ctxf[b8][2 * i + 1]);
  }
  __syncthreads();
  const unsigned short* WIC = (const unsigned short*)(ws + OFF_WICF);
  const int r = tid & 127, half = tid >> 7;
  for (int g = 0; g < 3; ++g) {
    const int row = g * 512 + hs * 128 + r;
    const uint* w = (const uint*)WIC + (size_t)row * 128 + half * 64;
    float acc[8] = {0.f, 0.f, 0.f, 0.f, 0.f, 0.f, 0.f, 0.f};
    for (int c8 = 0; c8 < 16; ++c8) {
      const uint4 w4 = *(const uint4*)(w + c8 * 4);
      #pragma unroll
      for (int b8 = 0; b8 < 8; ++b8) {
        const uint4 h4 = *(const uint4*)(&ctxh[b8][half * 64 + c8 * 4]);
        acc[b8] = fd2(w4.x, h4.x, acc[b8]);
        acc[b8] = fd2(w4.y, h4.y, acc[b8]);
        acc[b8] = fd2(w4.z, h4.z, acc[b8]);
        acc[b8] = fd2(w4.w, h4.w, acc[b8]);
      }
    }
    #pragma unroll
    for (int b8 = 0; b8 < 8; ++b8)
      pRed[((g * 2 + half) * 128 + r) * 8 + b8] = acc[b8];
  }
  __syncthreads();
  if (tid < 128) {
    float* H0 = (float*)(ws + OFF_H0);
    const float* GH0 = (const float*)(ws + OFF_GH0);
    const float* gtok = (const float*)(ws + OFF_GTOK);
    for (int b8 = 0; b8 < 8; ++b8) {
      const int b = bg * 8 + b8;
      const int tok = (t == 0) ? SOS : targets[(size_t)b * LL + t - 1];
      const float* gt = gtok + (size_t)tok * 1536 + hs * 128 + tid;
      const float* gh = GH0 + (size_t)b * 1536 + hs * 128 + tid;
      const float g0 = pRed[((0) * 128 + tid) * 8 + b8] + pRed[((1) * 128 + tid) * 8 + b8] + gt[0];
      const float g1 = pRed[((2) * 128 + tid) * 8 + b8] + pRed[((3) * 128 + tid) * 8 + b8] + gt[512];
      const float g2 = pRed[((4) * 128 + tid) * 8 + b8] + pRed[((5) * 128 + tid) * 8 + b8] + gt[1024];
      const float rg = sigmoid_fast(g0 + gh[0]);
      const float zg = sigmoid_fast(g1 + gh[512]);
      const float ng = tanh_fast(g2 + rg * gh[1024]);
      const size_t hi = (size_t)b * HH + hs * 128 + tid;
      H0[hi] = (1.f - zg) * ng + zg * H0[hi];
    }
  }
}

// K2b: gi1 + layer-1 gates -> H1. blocks (hs, bg).
__global__ __launch_bounds__(256) void k2b(char* ws, const float* bih1) {
  __shared__ uint hu[8][256];
  __shared__ float pRed[6 * 128 * 8];
  const int bid = blockIdx.x, tid = threadIdx.x;
  const int hs = bid >> 3, bg = bid & 7;
  const float* H0 = (const float*)(ws + OFF_H0);
  for (int p = 0; p < 8; ++p) {
    const int u = p * 256 + tid;
    const int b8 = u >> 8, i = u & 255;
    const float* hp = H0 + (size_t)(bg * 8 + b8) * HH + 2 * i;
    hu[b8][i] = packh(hp[0], hp[1]);
  }
  __syncthreads();
  const unsigned short* WI1 = (const unsigned short*)(ws + OFF_WI1F);
  const int r = tid & 127, half = tid >> 7;
  for (int g = 0; g < 3; ++g) {
    const int row = g * 512 + hs * 128 + r;
    const uint* w = (const uint*)WI1 + (size_t)row * 256 + half * 128;
    float acc[8] = {0.f, 0.f, 0.f, 0.f, 0.f, 0.f, 0.f, 0.f};
    for (int c8 = 0; c8 < 32; ++c8) {
      const uint4 w4 = *(const uint4*)(w + c8 * 4);
      #pragma unroll
      for (int b8 = 0; b8 < 8; ++b8) {
        const uint4 h4 = *(const uint4*)(&hu[b8][half * 128 + c8 * 4]);
        acc[b8] = fd2(w4.x, h4.x, acc[b8]);
        acc[b8] = fd2(w4.y, h4.y, acc[b8]);
        acc[b8] = fd2(w4.z, h4.z, acc[b8]);
        acc[b8] = fd2(w4.w, h4.w, acc[b8]);
      }
    }
    #pragma unroll
    for (int b8 = 0; b8 < 8; ++b8)
      pRed[((g * 2 + half) * 128 + r) * 8 + b8] = acc[b8];
  }
  __syncthreads();
  if (tid < 128) {
    float* H1 = (float*)(ws + OFF_H1);
    const float* GH1 = (const float*)(ws + OFF_GH1);
    for (int b8 = 0; b8 < 8; ++b8) {
      const int b = bg * 8 + b8;
      const float* gh = GH1 + (size_t)b * 1536 + hs * 128 + tid;
      const float g0 = pRed[((0) * 128 + tid) * 8 + b8] + pRed[((1) * 128 + tid) * 8 + b8]
                     + bih1[hs * 128 + tid];
      const float g1 = pRed[((2) * 128 + tid) * 8 + b8] + pRed[((3) * 128 + tid) * 8 + b8]
                     + bih1[512 + hs * 128 + tid];
      const float g2 = pRed[((4) * 128 + tid) * 8 + b8] + pRed[((5) * 128 + tid) * 8 + b8]
                     + bih1[1024 + hs * 128 + tid];
      const float rg = sigmoid_fast(g0 + gh[0]);
      const float zg = sigmoid_fast(g1 + gh[512]);
      const float ng = tanh_fast(g2 + rg * gh[1024]);
      const size_t hi = (size_t)b * HH + hs * 128 + tid;
      H1[hi] = (1.f - zg) * ng + zg * H1[hi];
    }
  }
}

// K2c: q = Wh@h1 + logits. blocks (qs = bid>>3, bg = bid&7).
__global__ __launch_bounds__(256) void k2c(char* ws, const float* Wout,
                                           const float* bout, float* out, int t) {
  __shared__ uint hu[8][256];
  __shared__ float pRed[2 * 128 * 8];
  const int bid = blockIdx.x, tid = threadIdx.x;
  const int qs = bid >> 3, bg = bid & 7;
  const float* H1 = (const float*)(ws + OFF_H1);
  for (int p = 0; p < 8; ++p) {
    const int u = p * 256 + tid;
    const int b8 = u >> 8, i = u & 255;
    const float* hp = H1 + (size_t)(bg * 8 + b8) * HH + 2 * i;
    hu[b8][i] = packh(hp[0], hp[1]);
  }
  __syncthreads();
  const unsigned short* WHF = (const unsigned short*)(ws + OFF_WHF);
  const int r = tid & 127, half = tid >> 7;
  {
    const int row = qs * 128 + r;
    const uint* w = (const uint*)WHF + (size_t)row * 256 + half * 128;
    float acc[8] = {0.f, 0.f, 0.f, 0.f, 0.f, 0.f, 0.f, 0.f};
    for (int c8 = 0; c8 < 32; ++c8) {
      const uint4 w4 = *(const uint4*)(w + c8 * 4);
      #pragma unroll
      for (int b8 = 0; b8 < 8; ++b8) {
        const uint4 h4 = *(const uint4*)(&hu[b8][half * 128 + c8 * 4]);
        acc[b8] = fd2(w4.x, h4.x, acc[b8]);
        acc[b8] = fd2(w4.y, h4.y, acc[b8]);
        acc[b8] = fd2(w4.z, h4.z, acc[b8]);
        acc[b8] = fd2(w4.w, h4.w, acc[b8]);
      }
    }
    #pragma unroll
    for (int b8 = 0; b8 < 8; ++b8)
      pRed[((half)*128 + r) * 8 + b8] = acc[b8];
  }
  __syncthreads();
  if (tid < 128) {
    float* Q = (float*)(ws + OFF_Q);
    for (int b8 = 0; b8 < 8; ++b8)
      Q[(size_t)(bg * 8 + b8) * HH + qs * 128 + tid] =
          pRed[((0) * 128 + tid) * 8 + b8] + pRed[((1) * 128 + tid) * 8 + b8];
  }
  if (qs == 0) {
    const int b8 = tid >> 5, v = (tid >> 3) & 3, kg = tid & 7;
    const float* h1 = H1 + (size_t)(bg * 8 + b8) * HH;
    float a = 0.f;
    for (int i = 0; i < 64; ++i)
      a += Wout[(size_t)v * HH + kg * 64 + i] * h1[kg * 64 + i];
    a += __shfl_xor(a, 1); a += __shfl_xor(a, 2); a += __shfl_xor(a, 4);
    if (kg == 0) out[((size_t)(bg * 8 + b8) * LL + t) * VV + v] = a + bout[v];
  }
}

// ---------------- launch ----------------
extern "C" void kernel_launch(void* const* d_in, const int* in_sizes, int n_in,
                              void* d_out, int out_size, void* d_ws, size_t ws_size,
                              hipStream_t stream) {
  char* ws = (char*)d_ws;
  const float* enc     = (const float*)d_in[0];
  const int*   targets = (const int*)d_in[1];
  const float* emb   = (const float*)d_in[4];
  const float* Wh    = (const float*)d_in[5];
  const float* Ws    = (const float*)d_in[6];
  const float* vvec  = (const float*)d_in[7];
  const float* Wih0  = (const float*)d_in[8];
  const float* Whh0  = (const float*)d_in[9];
  const float* bih0  = (const float*)d_in[10];
  const float* bhh0  = (const float*)d_in[11];
  const float* Wih1  = (const float*)d_in[12];
  const float* Whh1  = (const float*)d_in[13];
  const float* bih1  = (const float*)d_in[14];
  const float* bhh1  = (const float*)d_in[15];
  const float* Wout  = (const float*)d_in[16];
  const float* bout  = (const float*)d_in[17];
  const float* Winit = (const float*)d_in[18];
  const float* binit = (const float*)d_in[19];
  float* out = (float*)d_out;

  k_prep <<<1024, 256, 0, stream>>>(Wh, Whh0, Whh1, Wih1, Wih0, ws);
  k_keys <<<1024, 256, 0, stream>>>(enc, Ws, ws);
  k_encT <<<2048, 256, 0, stream>>>(enc, ws);
  k_gitok<<<6,    256, 0, stream>>>(emb, Wih0, bih0, ws);
  k_init <<<64,   256, 0, stream>>>(enc, Winit, binit, Wh, ws);

  for (int t = 0; t < LL; ++t) {
    k1 <<<576, 256, 0, stream>>>(ws, vvec, bhh0, bhh1);
    k2a<<<32,  256, 0, stream>>>(ws, targets, t);
    k2b<<<32,  256, 0, stream>>>(ws, bih1);
    k2c<<<32,  256, 0, stream>>>(ws, Wout, bout, out, t);
  }
}